// Round 17
// baseline (248.263 us; speedup 1.0000x reference)
//
#include <hip/hip_runtime.h>

#define T_STEPS 60
#define HID 128
#define ROWS 16
#define NBLK (16384 / ROWS)  // 1024 blocks x 256 threads

typedef __attribute__((ext_vector_type(8))) short short8;
typedef __attribute__((ext_vector_type(4))) float f32x4;

#define K1 1.44269504088896340736f  // log2(e)

__device__ __forceinline__ unsigned short f2bf(float f) {
  unsigned u = __float_as_uint(f);
  return (unsigned short)((u + 0x7fffu + ((u >> 16) & 1u)) >> 16);
}
__device__ __forceinline__ float sigm(float x) {
  return __builtin_amdgcn_rcpf(1.0f + __expf(-x));
}
// butterfly-add over the 16-lane DPP row (sums l15 dimension, preserves l4)
template <int CTRL>
__device__ __forceinline__ float dppadd(float x) {
  int y = __builtin_amdgcn_update_dpp(0, __builtin_bit_cast(int, x), CTRL, 0xf,
                                      0xf, false);
  return x + __builtin_bit_cast(float, y);
}

// LDS map (bytes):
//   [0,8192):      h dbuf: buf b at b*4096; 16 rows x 128 units bf16,
//                  row r at r*256, XOR-swizzled bits 4-6
//   [8192,40960):  xp f32, acc layout: slot (gt*2+j) at 8192+slot*4096+tid*16
//   [40960,41472): decode partial dbuf: buf b at 40960+b*256; wave w at w*64
//   [41472,45312): out staging [16 rows][60 t] f32
#define HB 0
#define XP 8192
#define PT 40960
#define OS 41472
#define LDS_BYTES 45312

// Occupancy algebra (R12/R15/R16 lessons): VGPR pool = 512/SIMD.
// bw is irreducible at 128KB/block of W_hh -> 128 regs/wave at 4 waves.
// Only shape with 2 barrier domains/CU AND 256-reg cap: 256-thr blocks
// (1 wave/SIMD), launch_bounds(256,2) -> cap 512/2 = 256, 2 blocks/CU.
// Loop peak ~215 regs < 256: no spill (canary: WRITE_SIZE == 3840 KB).
__global__ __launch_bounds__(256, 2) void lstm_fused(
    const float* __restrict__ x, const float* __restrict__ W_enc,
    const float* __restrict__ b_enc, const float* __restrict__ W_ih,
    const float* __restrict__ W_hh, const float* __restrict__ b_ih,
    const float* __restrict__ b_hh, const float* __restrict__ W_dec,
    const float* __restrict__ b_dec, float* __restrict__ out) {
  __shared__ __align__(16) unsigned char lds[LDS_BYTES];

  const int tid = threadIdx.x;
  const int wav = tid >> 6;  // 0..3 = unit-group
  const int lane = tid & 63;
  const int l15 = lane & 15;
  const int l4 = lane >> 4;
  const int u0 = wav * 32 + l15;  // first unit owned by this lane
  const int u1 = u0 + 16;         // second unit
  const int row0 = blockIdx.x * ROWS;
  float* OSf = (float*)(lds + OS);

  // zero h buf0 (4096 B)
  for (int i = tid; i < 1024; i += 256) ((unsigned*)(lds + HB))[i] = 0u;

  // ---- x rows for this lane (shared by both unit slots) ----
  float xr0[4], xr1[4], xr2[4];
#pragma unroll
  for (int v = 0; v < 4; ++v) {
    int r = 4 * l4 + v;
    const float* xp_ = x + (size_t)(row0 + r) * 3;
    xr0[v] = xp_[0];
    xr1[v] = xp_[1];
    xr2[v] = xp_[2];
  }

  // ---- xp = enc @ W_ih^T + b_ih + b_hh -> LDS f32 (exact), acc layout ----
  // (f16 xp was the R3/R5 failure: PRECISION, not location. f32 is exact.)
#pragma unroll
  for (int j = 0; j < 2; ++j) {
    const int u = u0 + j * 16;
    f32x4 xp4[4];
#pragma unroll
    for (int gt = 0; gt < 4; ++gt) {
      float bias = b_ih[gt * 128 + u] + b_hh[gt * 128 + u];
#pragma unroll
      for (int v = 0; v < 4; ++v) xp4[gt][v] = bias;
    }
    const f32x4* wp0 = (const f32x4*)(W_ih + (size_t)u * 64);
    const f32x4* wp1 = (const f32x4*)(W_ih + (size_t)(128 + u) * 64);
    const f32x4* wp2 = (const f32x4*)(W_ih + (size_t)(256 + u) * 64);
    const f32x4* wp3 = (const f32x4*)(W_ih + (size_t)(384 + u) * 64);
    for (int e4 = 0; e4 < 16; ++e4) {
      f32x4 w0 = wp0[e4], w1 = wp1[e4], w2 = wp2[e4], w3 = wp3[e4];
#pragma unroll
      for (int jj = 0; jj < 4; ++jj) {
        int e = e4 * 4 + jj;
        float we0 = W_enc[e * 3], we1 = W_enc[e * 3 + 1], we2 = W_enc[e * 3 + 2];
        float be = b_enc[e];
#pragma unroll
        for (int v = 0; v < 4; ++v) {
          float ev = fmaf(we0, xr0[v], fmaf(we1, xr1[v], fmaf(we2, xr2[v], be)));
          xp4[0][v] = fmaf(w0[jj], ev, xp4[0][v]);
          xp4[1][v] = fmaf(w1[jj], ev, xp4[1][v]);
          xp4[2][v] = fmaf(w2[jj], ev, xp4[2][v]);
          xp4[3][v] = fmaf(w3[jj], ev, xp4[3][v]);
        }
      }
    }
    // prescale into exp2 domain: -log2e (i,f,o), -2log2e (g); park in LDS
#pragma unroll
    for (int gt = 0; gt < 4; ++gt) {
      float s = (gt == 2) ? (-2.0f * K1) : (-K1);
#pragma unroll
      for (int v = 0; v < 4; ++v) xp4[gt][v] *= s;
      *(f32x4*)(lds + XP + (unsigned)(gt * 2 + j) * 4096 + (unsigned)tid * 16) =
          xp4[gt];
    }
  }

  // ---- W_hh bf16 B-fragments (units u0 and u1), exp2-prescaled ----
  short8 bwA[4][4], bwB[4][4];
#pragma unroll
  for (int gt = 0; gt < 4; ++gt) {
    float s = (gt == 2) ? (-2.0f * K1) : (-K1);
#pragma unroll
    for (int kt = 0; kt < 4; ++kt) {
      const float* pA = W_hh + (size_t)(gt * 128 + u0) * HID + kt * 32 + 8 * l4;
      const float* pB = W_hh + (size_t)(gt * 128 + u1) * HID + kt * 32 + 8 * l4;
      short8 fA, fB;
#pragma unroll
      for (int jj = 0; jj < 8; ++jj) {
        fA[jj] = (short)f2bf(s * pA[jj]);
        fB[jj] = (short)f2bf(s * pB[jj]);
      }
      bwA[gt][kt] = fA;
      bwB[gt][kt] = fB;
    }
  }

  // c in scaled domain: ct = -2log2e * c (e^{-2c} = 2^ct); [j*4+v]
  float ct[8] = {0.f, 0.f, 0.f, 0.f, 0.f, 0.f, 0.f, 0.f};

  // ---- LDS addresses (swizzle bits 4-6; +64 folded INSIDE the XOR — the
  //      R16 NaN was rd1 = rd0+64 carrying bit6->bit7) ----
  const unsigned swzA =
      (((unsigned)(l15 & 7)) << 4) ^ (((unsigned)(l15 & 8)) << 2);
  unsigned rd0 = ((unsigned)(l15 * 256 + l4 * 16)) ^ swzA;
  unsigned rd1 = ((unsigned)(l15 * 256 + l4 * 16 + 64)) ^ swzA;
  unsigned wrA[4], wrB[4];
  {
    unsigned rr = (unsigned)(4 * l4);
#define WRADDR(v, uu)                                                          \
  ((((rr + v) * 256 + (unsigned)(uu)*2) ^ (((rr + v) & 7u) << 4) ^             \
    (((rr + v) & 8u) << 2)) +                                                  \
   4096)
#pragma unroll
    for (int v = 0; v < 4; ++v) {
      wrA[v] = WRADDR(v, u0);
      wrB[v] = WRADDR(v, u1);
    }
#undef WRADDR
  }
  const float wd0 = W_dec[u0];
  const float wd1 = W_dec[u1];
  const unsigned ptA = PT + (unsigned)(wav * 64 + l4 * 16);
  const float kneg = -2.0f * K1;
  const float kpos = 2.0f * K1;

  __syncthreads();

  // gate math in exp2 domain (R7-verified):
  //   e^{-i}=2^a0, e^{-f}=2^a1, e^{-2g}=2^a2, e^{-o}=2^a3
  //   ct' = [ct*A*G + k(1-eg)*F]/(F*A*G), k=-2log2e;  h=(1-ec)/(Bo*(1+ec))
#pragma clang loop unroll(disable)
  for (int t = 0; t < T_STEPS; ++t) {
    // ---- duty reduce: cross-wave sum of step t-1 decode partials ----
    if (t > 0) {
      int tp = t - 1;
      if (wav == (tp & 3) && lane < 16) {
        unsigned base = PT + ((unsigned)(tp & 1) << 8) + (unsigned)(lane * 4);
        float s = 0.0f;
#pragma unroll
        for (int w2 = 0; w2 < 4; ++w2) s += *(const float*)(lds + base + w2 * 64);
        OSf[lane * T_STEPS + tp] = s;
      }
    }
    // ---- gates = xp + h @ W_hh^T (32 MFMAs: 4 gates x 2 unit-slots x 4 kt) ----
    short8 af0 = *(const short8*)(lds + rd0);
    short8 af1 = *(const short8*)(lds + rd1);
    short8 af2 = *(const short8*)(lds + rd0 + 128);
    short8 af3 = *(const short8*)(lds + rd1 + 128);
    f32x4 aA[4], aB[4];
#pragma unroll
    for (int gt = 0; gt < 4; ++gt) {
      f32x4 xA = *(const f32x4*)(lds + XP + (unsigned)(gt * 2 + 0) * 4096 +
                                 (unsigned)tid * 16);
      aA[gt] = __builtin_amdgcn_mfma_f32_16x16x32_bf16(af0, bwA[gt][0], xA, 0, 0, 0);
      f32x4 xB = *(const f32x4*)(lds + XP + (unsigned)(gt * 2 + 1) * 4096 +
                                 (unsigned)tid * 16);
      aB[gt] = __builtin_amdgcn_mfma_f32_16x16x32_bf16(af0, bwB[gt][0], xB, 0, 0, 0);
    }
#pragma unroll
    for (int gt = 0; gt < 4; ++gt) {
      aA[gt] = __builtin_amdgcn_mfma_f32_16x16x32_bf16(af1, bwA[gt][1], aA[gt], 0, 0, 0);
      aB[gt] = __builtin_amdgcn_mfma_f32_16x16x32_bf16(af1, bwB[gt][1], aB[gt], 0, 0, 0);
      aA[gt] = __builtin_amdgcn_mfma_f32_16x16x32_bf16(af2, bwA[gt][2], aA[gt], 0, 0, 0);
      aB[gt] = __builtin_amdgcn_mfma_f32_16x16x32_bf16(af2, bwB[gt][2], aB[gt], 0, 0, 0);
      aA[gt] = __builtin_amdgcn_mfma_f32_16x16x32_bf16(af3, bwA[gt][3], aA[gt], 0, 0, 0);
      aB[gt] = __builtin_amdgcn_mfma_f32_16x16x32_bf16(af3, bwB[gt][3], aB[gt], 0, 0, 0);
    }

    // ---- activations for 2 unit-slots x 4 rows ----
    float hA[4], hB[4];
    f32x4 pz;
#pragma unroll
    for (int j = 0; j < 2; ++j) {
#pragma unroll
      for (int v = 0; v < 4; ++v) {
        float pa0 = j ? aB[0][v] : aA[0][v];
        float pa1 = j ? aB[1][v] : aA[1][v];
        float pa2 = j ? aB[2][v] : aA[2][v];
        float pa3 = j ? aB[3][v] : aA[3][v];
        float ea = __builtin_amdgcn_exp2f(pa0);
        float ef = __builtin_amdgcn_exp2f(pa1);
        float eg = __builtin_amdgcn_exp2f(pa2);
        float eo = __builtin_amdgcn_exp2f(pa3);
        float A = 1.0f + ea, F = 1.0f + ef, G = 1.0f + eg, Bo = 1.0f + eo;
        float AG = A * G;
        float r = __builtin_amdgcn_rcpf(F * AG);
        float tt = fmaf(kpos, eg, kneg);
        float num = fmaf(ct[j * 4 + v], AG, tt * F);
        float cn = num * r;
        ct[j * 4 + v] = cn;
        float ec = __builtin_amdgcn_exp2f(cn);
        float r2 = __builtin_amdgcn_rcpf(Bo * (1.0f + ec));
        float hh = (1.0f - ec) * r2;
        if (j) hB[v] = hh; else hA[v] = hh;
      }
    }
#pragma unroll
    for (int v = 0; v < 4; ++v) pz[v] = fmaf(hA[v], wd0, hB[v] * wd1);
    // pack + store h (RTNE cvt_pk == f2bf rounding)
    unsigned rA01, rA23, rB01, rB23;
    asm("v_cvt_pk_bf16_f32 %0, %1, %2" : "=v"(rA01) : "v"(hA[0]), "v"(hA[1]));
    asm("v_cvt_pk_bf16_f32 %0, %1, %2" : "=v"(rA23) : "v"(hA[2]), "v"(hA[3]));
    asm("v_cvt_pk_bf16_f32 %0, %1, %2" : "=v"(rB01) : "v"(hB[0]), "v"(hB[1]));
    asm("v_cvt_pk_bf16_f32 %0, %1, %2" : "=v"(rB23) : "v"(hB[2]), "v"(hB[3]));
    *(unsigned short*)(lds + wrA[0]) = (unsigned short)rA01;
    *(unsigned short*)(lds + wrA[1]) = (unsigned short)(rA01 >> 16);
    *(unsigned short*)(lds + wrA[2]) = (unsigned short)rA23;
    *(unsigned short*)(lds + wrA[3]) = (unsigned short)(rA23 >> 16);
    *(unsigned short*)(lds + wrB[0]) = (unsigned short)rB01;
    *(unsigned short*)(lds + wrB[1]) = (unsigned short)(rB01 >> 16);
    *(unsigned short*)(lds + wrB[2]) = (unsigned short)rB23;
    *(unsigned short*)(lds + wrB[3]) = (unsigned short)(rB23 >> 16);
    // decode partial: 16-lane (l15) DPP butterfly, l4 rows preserved
#pragma unroll
    for (int v = 0; v < 4; ++v)
      pz[v] = dppadd<0x140>(dppadd<0x141>(dppadd<0x4E>(dppadd<0xB1>(pz[v]))));
    if (l15 == 0) *(f32x4*)(lds + ptA + ((unsigned)(t & 1) << 8)) = pz;
    __syncthreads();
    rd0 ^= 4096; rd1 ^= 4096;
#pragma unroll
    for (int v = 0; v < 4; ++v) { wrA[v] ^= 4096; wrB[v] ^= 4096; }
  }

  // ---- drain: reduce t=59 partials ----
  if (wav == (59 & 3) && lane < 16) {
    unsigned base = PT + ((unsigned)(59 & 1) << 8) + (unsigned)(lane * 4);
    float s = 0.0f;
#pragma unroll
    for (int w2 = 0; w2 < 4; ++w2) s += *(const float*)(lds + base + w2 * 64);
    OSf[lane * T_STEPS + 59] = s;
  }
  __syncthreads();

  // ---- epilogue: sigmoid + coalesced store ----
  const float bdec = b_dec[0];
  for (int i = tid; i < ROWS * T_STEPS; i += 256)
    out[(size_t)row0 * T_STEPS + i] = sigm(OSf[i] + bdec);
}

extern "C" void kernel_launch(void* const* d_in, const int* in_sizes, int n_in,
                              void* d_out, int out_size, void* d_ws, size_t ws_size,
                              hipStream_t stream) {
  const float* x = (const float*)d_in[0];
  const float* W_enc = (const float*)d_in[1];
  const float* b_enc = (const float*)d_in[2];
  const float* W_ih = (const float*)d_in[3];
  const float* W_hh = (const float*)d_in[4];
  const float* b_ih = (const float*)d_in[5];
  const float* b_hh = (const float*)d_in[6];
  const float* W_dec = (const float*)d_in[7];
  const float* b_dec = (const float*)d_in[8];
  float* out = (float*)d_out;

  dim3 grid(NBLK);  // 1024 blocks x 16 rows
  dim3 block(256);
  lstm_fused<<<grid, block, 0, stream>>>(x, W_enc, b_enc, W_ih, W_hh, b_ih, b_hh,
                                         W_dec, b_dec, out);
}